// Round 1
// baseline (2210.072 us; speedup 1.0000x reference)
//
#include <hip/hip_runtime.h>
#include <cstdint>
#include <cstddef>

#define NB 64
#define NP 24564
#define NC 81
#define NT 50
#define NROWS (NB*NP)   // 1,572,096
#define TCH 10          // truths per block in best-prior kernel

__device__ __forceinline__ unsigned long long umax64(unsigned long long a, unsigned long long b){
  return a > b ? a : b;
}

// ---------------------------------------------------------------------------
// Kernel A: per (b,p) best truth (max + first-occurrence argmax over T)
// ---------------------------------------------------------------------------
__global__ __launch_bounds__(256) void k_match(
    const float* __restrict__ priors, const float* __restrict__ tboxes,
    float* __restrict__ bto, int* __restrict__ bti)
{
  __shared__ float tb[NT*4];
  __shared__ float ta[NT];
  const int tid = threadIdx.x;
  const int b = blockIdx.y;
  if (tid < NT*4) tb[tid] = tboxes[b*NT*4 + tid];
  __syncthreads();
  if (tid < NT) ta[tid] = (tb[tid*4+2]-tb[tid*4+0]) * (tb[tid*4+3]-tb[tid*4+1]);
  __syncthreads();
  const int p = blockIdx.x*256 + tid;
  if (p >= NP) return;
  const float4 pr = ((const float4* __restrict__)priors)[p];
  const float px1 = pr.x - 0.5f*pr.z, py1 = pr.y - 0.5f*pr.w;
  const float px2 = pr.x + 0.5f*pr.z, py2 = pr.y + 0.5f*pr.w;
  const float pa  = pr.z * pr.w;
  float best = -1.0f; int bidx = 0;
  for (int t = 0; t < NT; ++t){
    const float x1 = tb[t*4+0], y1 = tb[t*4+1], x2 = tb[t*4+2], y2 = tb[t*4+3];
    float ix = fminf(x2, px2) - fmaxf(x1, px1);
    float iy = fminf(y2, py2) - fmaxf(y1, py1);
    ix = fmaxf(ix, 0.0f); iy = fmaxf(iy, 0.0f);
    const float inter = ix * iy;
    const float iou = inter / (ta[t] + pa - inter);
    if (iou > best){ best = iou; bidx = t; }   // strict > keeps first occurrence
  }
  bto[b*NP + p] = best;
  bti[b*NP + p] = bidx;
}

// ---------------------------------------------------------------------------
// Kernel A2: per (b,t) best prior (argmax over P). One block per (b, t-chunk),
// packed u64 key = (iou_bits<<32) | ~p  -> max = (max iou, then smallest p).
// ---------------------------------------------------------------------------
__global__ __launch_bounds__(256) void k_bestprior(
    const float* __restrict__ priors, const float* __restrict__ tboxes,
    int* __restrict__ bpi)
{
  __shared__ float tb[TCH*4];
  __shared__ float ta[TCH];
  __shared__ unsigned long long red[256*TCH];   // 20 KB
  const int tid = threadIdx.x;
  const int b  = blockIdx.x;
  const int t0 = blockIdx.y * TCH;
  if (tid < TCH*4) tb[tid] = tboxes[(b*NT + t0)*4 + tid];
  __syncthreads();
  if (tid < TCH) ta[tid] = (tb[tid*4+2]-tb[tid*4+0]) * (tb[tid*4+3]-tb[tid*4+1]);
  __syncthreads();

  unsigned long long best[TCH];
  #pragma unroll
  for (int j = 0; j < TCH; ++j) best[j] = 0ULL;

  for (int i = tid; i < NP; i += 256){
    const float4 pr = ((const float4* __restrict__)priors)[i];
    const float px1 = pr.x - 0.5f*pr.z, py1 = pr.y - 0.5f*pr.w;
    const float px2 = pr.x + 0.5f*pr.z, py2 = pr.y + 0.5f*pr.w;
    const float pa  = pr.z * pr.w;
    const unsigned long long low = (unsigned long long)(~(unsigned)i);
    #pragma unroll
    for (int j = 0; j < TCH; ++j){
      float ix = fminf(tb[j*4+2], px2) - fmaxf(tb[j*4+0], px1);
      float iy = fminf(tb[j*4+3], py2) - fmaxf(tb[j*4+1], py1);
      ix = fmaxf(ix, 0.0f); iy = fmaxf(iy, 0.0f);
      const float inter = ix * iy;
      const float iou = inter / (ta[j] + pa - inter);
      const unsigned long long key =
          ((unsigned long long)__float_as_uint(iou) << 32) | low;
      best[j] = umax64(best[j], key);
    }
  }
  #pragma unroll
  for (int j = 0; j < TCH; ++j) red[tid*TCH + j] = best[j];
  __syncthreads();
  for (int s = 128; s > 0; s >>= 1){
    if (tid < s){
      #pragma unroll
      for (int j = 0; j < TCH; ++j)
        red[tid*TCH + j] = umax64(red[tid*TCH + j], red[(tid+s)*TCH + j]);
    }
    __syncthreads();
  }
  if (tid < TCH)
    bpi[b*NT + t0 + tid] = (int)(~(unsigned)(red[tid] & 0xffffffffULL));
}

// ---------------------------------------------------------------------------
// Kernel B: sequential (last-write-wins) override, one thread per image
// ---------------------------------------------------------------------------
__global__ void k_force(const int* __restrict__ bpi,
                        float* __restrict__ bto, int* __restrict__ bti)
{
  const int b = threadIdx.x;
  if (b >= NB) return;
  for (int t = 0; t < NT; ++t){
    const int p = bpi[b*NT + t];
    bto[b*NP + p] = 2.0f;
    bti[b*NP + p] = t;
  }
}

// ---------------------------------------------------------------------------
// Kernel C: fused CE (logsumexp - gathered logit), positive loc loss, counts.
// 16 lanes per row; block = 256 threads = 16 rows.
// ---------------------------------------------------------------------------
__global__ __launch_bounds__(256) void k_ce(
    const float* __restrict__ conf, const float* __restrict__ loc,
    const float* __restrict__ priors, const float* __restrict__ tboxes,
    const int* __restrict__ tlabels,
    const float* __restrict__ bto, const int* __restrict__ bti,
    float* __restrict__ mine, float* __restrict__ ce_pos,
    float* __restrict__ loss_l, int* __restrict__ num_pos)
{
  const int tid = threadIdx.x;
  const int g = tid >> 4;          // row within block
  const int l = tid & 15;          // lane within row
  const int r = blockIdx.x*16 + g;
  if (r >= NROWS) return;
  const unsigned b = (unsigned)r / NP;
  const int p = r - (int)b*NP;
  const size_t base = (size_t)r * NC;

  float v[5];
  #pragma unroll
  for (int j = 0; j < 5; ++j) v[j] = conf[base + l + 16*j];
  const float v5 = (l == 0) ? conf[base + 80] : -INFINITY;

  float m = v5;
  #pragma unroll
  for (int j = 0; j < 5; ++j) m = fmaxf(m, v[j]);
  #pragma unroll
  for (int off = 1; off < 16; off <<= 1) m = fmaxf(m, __shfl_xor(m, off, 16));

  const float ov = bto[r];
  const int ti = bti[r];
  const int cls = (ov < 0.5f) ? 0 : (tlabels[b*NT + ti] + 1);

  float se = 0.0f, lg = 0.0f;
  #pragma unroll
  for (int j = 0; j < 5; ++j){
    se += __expf(v[j] - m);
    if (l + 16*j == cls) lg = v[j];
  }
  if (l == 0){
    se += __expf(v5 - m);
    if (cls == 80) lg = v5;
  }
  #pragma unroll
  for (int off = 1; off < 16; off <<= 1){
    se += __shfl_xor(se, off, 16);
    lg += __shfl_xor(lg, off, 16);
  }
  const float ce = m + __logf(se) - lg;

  if (l == 0){
    const bool pos = cls > 0;
    mine[r] = pos ? 0.0f : ce;
    if (pos){
      atomicAdd(&ce_pos[b], ce);
      atomicAdd(&num_pos[b], 1);
      const float4 pr = ((const float4* __restrict__)priors)[p];
      const float4 t4 = ((const float4* __restrict__)tboxes)[b*NT + ti];
      const float gcx = ((t4.x + t4.z)*0.5f - pr.x) / (0.1f*pr.z);
      const float gcy = ((t4.y + t4.w)*0.5f - pr.y) / (0.1f*pr.w);
      const float gw  = __logf((t4.z - t4.x) / pr.z) * 5.0f;
      const float gh  = __logf((t4.w - t4.y) / pr.w) * 5.0f;
      const float4 ld = ((const float4* __restrict__)loc)[r];
      float s = 0.0f;
      {
        float d, ad;
        d = ld.x - gcx; ad = fabsf(d); s += (ad < 1.0f) ? 0.5f*d*d : ad - 0.5f;
        d = ld.y - gcy; ad = fabsf(d); s += (ad < 1.0f) ? 0.5f*d*d : ad - 0.5f;
        d = ld.z - gw;  ad = fabsf(d); s += (ad < 1.0f) ? 0.5f*d*d : ad - 0.5f;
        d = ld.w - gh;  ad = fabsf(d); s += (ad < 1.0f) ? 0.5f*d*d : ad - 0.5f;
      }
      atomicAdd(&loss_l[b], s);
    }
  }
}

// ---------------------------------------------------------------------------
// Kernel D: exact top-k sum per image via 4-pass radix select on float bits
// ---------------------------------------------------------------------------
__global__ __launch_bounds__(256) void k_topk(
    const float* __restrict__ mine, const int* __restrict__ num_pos,
    float* __restrict__ topk)
{
  const int b = blockIdx.x;
  const int tid = threadIdx.x;
  const float* __restrict__ d = mine + (size_t)b * NP;
  const int k = min(3 * num_pos[b], NP - 1);

  __shared__ unsigned hist[256];
  __shared__ unsigned sfx[257];
  __shared__ unsigned s_prefix;
  __shared__ int s_rem;
  __shared__ float s_sum;

  if (k <= 0){
    if (tid == 0) topk[b] = 0.0f;
    return;
  }
  if (tid == 0){ s_prefix = 0u; s_rem = k; s_sum = 0.0f; }
  __syncthreads();

  for (int pass = 0; pass < 4; ++pass){
    const int shift = 24 - pass*8;
    hist[tid] = 0u;
    __syncthreads();
    const unsigned pref = s_prefix;
    for (int i = tid; i < NP; i += 256){
      const unsigned u = __float_as_uint(d[i]);
      const bool cand = (pass == 0) || ((u >> (shift + 8)) == pref);
      if (cand) atomicAdd(&hist[(u >> shift) & 255u], 1u);
    }
    __syncthreads();
    sfx[tid] = hist[tid];
    if (tid == 0) sfx[256] = 0u;
    __syncthreads();
    for (int off = 1; off < 256; off <<= 1){
      const unsigned add = (tid + off < 256) ? sfx[tid + off] : 0u;
      __syncthreads();
      sfx[tid] += add;
      __syncthreads();
    }
    const int rem = s_rem;
    __syncthreads();   // everyone has read s_rem before selector overwrites
    if ((int)sfx[tid] >= rem && (int)sfx[tid + 1] < rem){
      s_prefix = (pref << 8) | (unsigned)tid;
      s_rem = rem - (int)sfx[tid + 1];
    }
    __syncthreads();
  }

  const unsigned kb = s_prefix;
  const int rem = s_rem;
  const float kv = __uint_as_float(kb);
  float acc = 0.0f;
  for (int i = tid; i < NP; i += 256){
    const float x = d[i];
    if (__float_as_uint(x) > kb) acc += x;
  }
  atomicAdd(&s_sum, acc);
  __syncthreads();
  if (tid == 0) topk[b] = s_sum + (float)rem * kv;
}

// ---------------------------------------------------------------------------
// Kernel E: final combine
// ---------------------------------------------------------------------------
__global__ void k_final(const int* __restrict__ num_pos,
                        const float* __restrict__ loss_l,
                        const float* __restrict__ ce_pos,
                        const float* __restrict__ topk,
                        float* __restrict__ out)
{
  const int tid = threadIdx.x;
  int   np = num_pos[tid];
  float ll = loss_l[tid];
  float cp = ce_pos[tid];
  float tk = topk[tid];
  #pragma unroll
  for (int off = 32; off > 0; off >>= 1){
    np += __shfl_down(np, off);
    ll += __shfl_down(ll, off);
    cp += __shfl_down(cp, off);
    tk += __shfl_down(tk, off);
  }
  if (tid == 0){
    const float n = (float)max(np, 1);
    out[0] = ll / n;
    out[1] = (cp + tk) / n;
  }
}

// ---------------------------------------------------------------------------
extern "C" void kernel_launch(void* const* d_in, const int* in_sizes, int n_in,
                              void* d_out, int out_size, void* d_ws, size_t ws_size,
                              hipStream_t stream)
{
  const float* loc     = (const float*)d_in[0];
  const float* conf    = (const float*)d_in[1];
  const float* priors  = (const float*)d_in[2];
  const float* tboxes  = (const float*)d_in[3];
  const int*   tlabels = (const int*)d_in[4];
  float* out = (float*)d_out;

  char* ws = (char*)d_ws;
  int*   num_pos = (int*)(ws + 0);        // 64
  float* loss_l  = (float*)(ws + 256);    // 64
  float* ce_pos  = (float*)(ws + 512);    // 64
  float* topk    = (float*)(ws + 768);    // 64
  float* bto  = (float*)(ws + 1024);
  int*   bti  = (int*)  (ws + 1024 + 4*(size_t)NROWS);
  float* mine = (float*)(ws + 1024 + 8*(size_t)NROWS);
  int*   bpi  = (int*)  (ws + 1024 + 12*(size_t)NROWS);   // 3200 ints

  hipMemsetAsync(ws, 0, 1024, stream);

  dim3 gA((NP + 255)/256, NB);
  k_match<<<gA, 256, 0, stream>>>(priors, tboxes, bto, bti);

  dim3 gA2(NB, NT/TCH);
  k_bestprior<<<gA2, 256, 0, stream>>>(priors, tboxes, bpi);

  k_force<<<1, 64, 0, stream>>>(bpi, bto, bti);

  k_ce<<<(NROWS + 15)/16, 256, 0, stream>>>(conf, loc, priors, tboxes, tlabels,
                                            bto, bti, mine, ce_pos, loss_l, num_pos);

  k_topk<<<NB, 256, 0, stream>>>(mine, num_pos, topk);

  k_final<<<1, 64, 0, stream>>>(num_pos, loss_l, ce_pos, topk, out);
}

// Round 2
// 880.481 us; speedup vs baseline: 2.5101x; 2.5101x over previous
//
#include <hip/hip_runtime.h>
#include <cstdint>
#include <cstddef>

#define NB 64
#define NP 24564
#define NC 81
#define NT 50
#define NROWS (NB*NP)   // 1,572,096
#define TCH 10          // truths per block in best-prior kernel
#define NSEG 8          // P-segments in best-prior kernel
#define SEGLEN ((NP + NSEG - 1)/NSEG)   // 3071

__device__ __forceinline__ unsigned long long umax64(unsigned long long a, unsigned long long b){
  return a > b ? a : b;
}

// ---------------------------------------------------------------------------
// Kernel A: per (b,p) best truth (max + first-occurrence argmax over T)
// ---------------------------------------------------------------------------
__global__ __launch_bounds__(256) void k_match(
    const float* __restrict__ priors, const float* __restrict__ tboxes,
    float* __restrict__ bto, int* __restrict__ bti)
{
  __shared__ float tb[NT*4];
  __shared__ float ta[NT];
  const int tid = threadIdx.x;
  const int b = blockIdx.y;
  if (tid < NT*4) tb[tid] = tboxes[b*NT*4 + tid];
  __syncthreads();
  if (tid < NT) ta[tid] = (tb[tid*4+2]-tb[tid*4+0]) * (tb[tid*4+3]-tb[tid*4+1]);
  __syncthreads();
  const int p = blockIdx.x*256 + tid;
  if (p >= NP) return;
  const float4 pr = ((const float4* __restrict__)priors)[p];
  const float px1 = pr.x - 0.5f*pr.z, py1 = pr.y - 0.5f*pr.w;
  const float px2 = pr.x + 0.5f*pr.z, py2 = pr.y + 0.5f*pr.w;
  const float pa  = pr.z * pr.w;
  float best = -1.0f; int bidx = 0;
  for (int t = 0; t < NT; ++t){
    const float x1 = tb[t*4+0], y1 = tb[t*4+1], x2 = tb[t*4+2], y2 = tb[t*4+3];
    float ix = fminf(x2, px2) - fmaxf(x1, px1);
    float iy = fminf(y2, py2) - fmaxf(y1, py1);
    ix = fmaxf(ix, 0.0f); iy = fmaxf(iy, 0.0f);
    const float inter = ix * iy;
    const float iou = inter / (ta[t] + pa - inter);
    if (iou > best){ best = iou; bidx = t; }   // strict > keeps first occurrence
  }
  bto[b*NP + p] = best;
  bti[b*NP + p] = bidx;
}

// ---------------------------------------------------------------------------
// Kernel A2: per (b,t) best prior (argmax over P), P split into NSEG segments.
// packed u64 key = (iou_bits<<32) | ~p  -> max = (max iou, then smallest p).
// Partials merged with global atomicMax into bpk (zeroed by memset).
// ---------------------------------------------------------------------------
__global__ __launch_bounds__(256) void k_bestprior(
    const float* __restrict__ priors, const float* __restrict__ tboxes,
    unsigned long long* __restrict__ bpk)
{
  __shared__ float tb[TCH*4];
  __shared__ float ta[TCH];
  __shared__ unsigned long long red[256*TCH];   // 20 KB
  const int tid = threadIdx.x;
  const int b  = blockIdx.x;
  const int t0 = blockIdx.y * TCH;
  const int i0 = blockIdx.z * SEGLEN;
  const int iend = min(i0 + SEGLEN, NP);
  if (tid < TCH*4) tb[tid] = tboxes[(b*NT + t0)*4 + tid];
  __syncthreads();
  if (tid < TCH) ta[tid] = (tb[tid*4+2]-tb[tid*4+0]) * (tb[tid*4+3]-tb[tid*4+1]);
  __syncthreads();

  unsigned long long best[TCH];
  #pragma unroll
  for (int j = 0; j < TCH; ++j) best[j] = 0ULL;

  for (int i = i0 + tid; i < iend; i += 256){
    const float4 pr = ((const float4* __restrict__)priors)[i];
    const float px1 = pr.x - 0.5f*pr.z, py1 = pr.y - 0.5f*pr.w;
    const float px2 = pr.x + 0.5f*pr.z, py2 = pr.y + 0.5f*pr.w;
    const float pa  = pr.z * pr.w;
    const unsigned long long low = (unsigned long long)(~(unsigned)i);
    #pragma unroll
    for (int j = 0; j < TCH; ++j){
      float ix = fminf(tb[j*4+2], px2) - fmaxf(tb[j*4+0], px1);
      float iy = fminf(tb[j*4+3], py2) - fmaxf(tb[j*4+1], py1);
      ix = fmaxf(ix, 0.0f); iy = fmaxf(iy, 0.0f);
      const float inter = ix * iy;
      const float iou = inter / (ta[j] + pa - inter);
      const unsigned long long key =
          ((unsigned long long)__float_as_uint(iou) << 32) | low;
      best[j] = umax64(best[j], key);
    }
  }
  #pragma unroll
  for (int j = 0; j < TCH; ++j) red[tid*TCH + j] = best[j];
  __syncthreads();
  for (int s = 128; s > 0; s >>= 1){
    if (tid < s){
      #pragma unroll
      for (int j = 0; j < TCH; ++j)
        red[tid*TCH + j] = umax64(red[tid*TCH + j], red[(tid+s)*TCH + j]);
    }
    __syncthreads();
  }
  if (tid < TCH)
    atomicMax(&bpk[b*NT + t0 + tid], red[tid]);
}

// ---------------------------------------------------------------------------
// Kernel B: sequential (last-write-wins) override, one thread per image
// ---------------------------------------------------------------------------
__global__ void k_force(const unsigned long long* __restrict__ bpk,
                        float* __restrict__ bto, int* __restrict__ bti)
{
  const int b = threadIdx.x;
  if (b >= NB) return;
  for (int t = 0; t < NT; ++t){
    const int p = (int)(~(unsigned)(bpk[b*NT + t] & 0xffffffffULL));
    bto[b*NP + p] = 2.0f;
    bti[b*NP + p] = t;
  }
}

// ---------------------------------------------------------------------------
// Kernel C: fused CE + positive loc loss + counts. One THREAD per row.
// Row (81 floats, 324 B, only 4B-aligned) loaded as the enclosing aligned
// 84-float window (21 float4); <=3 boundary elems per side masked to -inf
// (exp(-inf - m) == 0 keeps the softmax exact). Two-pass max/sum in regs,
// no shuffles in the hot path; block-level reduction -> 3 atomics per block.
// ---------------------------------------------------------------------------
__global__ __launch_bounds__(256) void k_ce(
    const float* __restrict__ conf, const float* __restrict__ loc,
    const float* __restrict__ priors, const float* __restrict__ tboxes,
    const int* __restrict__ tlabels,
    const float* __restrict__ bto, const int* __restrict__ bti,
    float* __restrict__ mine, float* __restrict__ ce_pos,
    float* __restrict__ loss_l, int* __restrict__ num_pos)
{
  const int tid = threadIdx.x;
  const int b = blockIdx.y;
  const int p0 = blockIdx.x*256 + tid;
  const bool active = p0 < NP;
  const int p = active ? p0 : (NP - 1);
  const int r = b*NP + p;
  const size_t e0 = (size_t)r * NC;          // element index of row start
  const size_t a0 = e0 & ~(size_t)3;         // 16B-aligned window start
  const int s = (int)(e0 & 3);               // row offset within window

  const float4* __restrict__ c4 = (const float4* __restrict__)conf + (a0 >> 2);
  float4 w[21];
  #pragma unroll
  for (int j = 0; j < 21; ++j) w[j] = c4[j];

  const float ov = bto[r];
  const int   ti = bti[r];
  const int  cls = (ov < 0.5f) ? 0 : (tlabels[b*NT + ti] + 1);
  const float lg = conf[e0 + cls];           // gathered logit (L1-hit)

  // mask window elements outside [s, s+80]
  const float NI = -INFINITY;
  w[0].x  = (s > 0) ? NI : w[0].x;    // idx 0
  w[0].y  = (s > 1) ? NI : w[0].y;    // idx 1
  w[0].z  = (s > 2) ? NI : w[0].z;    // idx 2
  w[20].y = (s < 1) ? NI : w[20].y;   // idx 81
  w[20].z = (s < 2) ? NI : w[20].z;   // idx 82
  w[20].w = (s < 3) ? NI : w[20].w;   // idx 83

  float m = w[0].w;
  #pragma unroll
  for (int j = 0; j < 21; ++j)
    m = fmaxf(m, fmaxf(fmaxf(w[j].x, w[j].y), fmaxf(w[j].z, w[j].w)));

  float a0s = 0.f, a1s = 0.f, a2s = 0.f, a3s = 0.f;
  #pragma unroll
  for (int j = 0; j < 21; ++j){
    a0s += __expf(w[j].x - m);
    a1s += __expf(w[j].y - m);
    a2s += __expf(w[j].z - m);
    a3s += __expf(w[j].w - m);
  }
  const float ce = m + __logf((a0s + a1s) + (a2s + a3s)) - lg;

  const bool pos = active && (cls > 0);
  if (active) mine[r] = pos ? 0.0f : ce;

  float cp = pos ? ce : 0.0f;
  float ll = 0.0f;
  int   pc = pos ? 1 : 0;
  if (pos){
    const float4 pr = ((const float4* __restrict__)priors)[p];
    const float4 t4 = ((const float4* __restrict__)tboxes)[b*NT + ti];
    const float gcx = ((t4.x + t4.z)*0.5f - pr.x) / (0.1f*pr.z);
    const float gcy = ((t4.y + t4.w)*0.5f - pr.y) / (0.1f*pr.w);
    const float gw  = __logf((t4.z - t4.x) / pr.z) * 5.0f;
    const float gh  = __logf((t4.w - t4.y) / pr.w) * 5.0f;
    const float4 ld = ((const float4* __restrict__)loc)[r];
    float d, ad;
    d = ld.x - gcx; ad = fabsf(d); ll += (ad < 1.0f) ? 0.5f*d*d : ad - 0.5f;
    d = ld.y - gcy; ad = fabsf(d); ll += (ad < 1.0f) ? 0.5f*d*d : ad - 0.5f;
    d = ld.z - gw;  ad = fabsf(d); ll += (ad < 1.0f) ? 0.5f*d*d : ad - 0.5f;
    d = ld.w - gh;  ad = fabsf(d); ll += (ad < 1.0f) ? 0.5f*d*d : ad - 0.5f;
  }

  // wave -> block reduction, 3 atomics per block total
  #pragma unroll
  for (int off = 32; off > 0; off >>= 1){
    cp += __shfl_down(cp, off);
    ll += __shfl_down(ll, off);
    pc += __shfl_down(pc, off);
  }
  __shared__ float rcp[4], rll[4];
  __shared__ int rpc[4];
  const int wv = tid >> 6;
  if ((tid & 63) == 0){ rcp[wv] = cp; rll[wv] = ll; rpc[wv] = pc; }
  __syncthreads();
  if (tid == 0){
    atomicAdd(&ce_pos[b], (rcp[0]+rcp[1])+(rcp[2]+rcp[3]));
    atomicAdd(&loss_l[b], (rll[0]+rll[1])+(rll[2]+rll[3]));
    atomicAdd(&num_pos[b], (rpc[0]+rpc[1])+(rpc[2]+rpc[3]));
  }
}

// ---------------------------------------------------------------------------
// Kernel D: exact top-k sum per image via 4-pass radix select on float bits
// ---------------------------------------------------------------------------
__global__ __launch_bounds__(256) void k_topk(
    const float* __restrict__ mine, const int* __restrict__ num_pos,
    float* __restrict__ topk)
{
  const int b = blockIdx.x;
  const int tid = threadIdx.x;
  const float* __restrict__ d = mine + (size_t)b * NP;
  const int k = min(3 * num_pos[b], NP - 1);

  __shared__ unsigned hist[256];
  __shared__ unsigned sfx[257];
  __shared__ unsigned s_prefix;
  __shared__ int s_rem;
  __shared__ float s_sum;

  if (k <= 0){
    if (tid == 0) topk[b] = 0.0f;
    return;
  }
  if (tid == 0){ s_prefix = 0u; s_rem = k; s_sum = 0.0f; }
  __syncthreads();

  for (int pass = 0; pass < 4; ++pass){
    const int shift = 24 - pass*8;
    hist[tid] = 0u;
    __syncthreads();
    const unsigned pref = s_prefix;
    #pragma unroll 4
    for (int i = tid; i < NP; i += 256){
      const unsigned u = __float_as_uint(d[i]);
      const bool cand = (pass == 0) || ((u >> (shift + 8)) == pref);
      if (cand) atomicAdd(&hist[(u >> shift) & 255u], 1u);
    }
    __syncthreads();
    sfx[tid] = hist[tid];
    if (tid == 0) sfx[256] = 0u;
    __syncthreads();
    for (int off = 1; off < 256; off <<= 1){
      const unsigned add = (tid + off < 256) ? sfx[tid + off] : 0u;
      __syncthreads();
      sfx[tid] += add;
      __syncthreads();
    }
    const int rem = s_rem;
    __syncthreads();   // everyone has read s_rem before selector overwrites
    if ((int)sfx[tid] >= rem && (int)sfx[tid + 1] < rem){
      s_prefix = (pref << 8) | (unsigned)tid;
      s_rem = rem - (int)sfx[tid + 1];
    }
    __syncthreads();
  }

  const unsigned kb = s_prefix;
  const int rem = s_rem;
  const float kv = __uint_as_float(kb);
  float acc = 0.0f;
  #pragma unroll 4
  for (int i = tid; i < NP; i += 256){
    const float x = d[i];
    if (__float_as_uint(x) > kb) acc += x;
  }
  atomicAdd(&s_sum, acc);
  __syncthreads();
  if (tid == 0) topk[b] = s_sum + (float)rem * kv;
}

// ---------------------------------------------------------------------------
// Kernel E: final combine
// ---------------------------------------------------------------------------
__global__ void k_final(const int* __restrict__ num_pos,
                        const float* __restrict__ loss_l,
                        const float* __restrict__ ce_pos,
                        const float* __restrict__ topk,
                        float* __restrict__ out)
{
  const int tid = threadIdx.x;
  int   np = num_pos[tid];
  float ll = loss_l[tid];
  float cp = ce_pos[tid];
  float tk = topk[tid];
  #pragma unroll
  for (int off = 32; off > 0; off >>= 1){
    np += __shfl_down(np, off);
    ll += __shfl_down(ll, off);
    cp += __shfl_down(cp, off);
    tk += __shfl_down(tk, off);
  }
  if (tid == 0){
    const float n = (float)max(np, 1);
    out[0] = ll / n;
    out[1] = (cp + tk) / n;
  }
}

// ---------------------------------------------------------------------------
extern "C" void kernel_launch(void* const* d_in, const int* in_sizes, int n_in,
                              void* d_out, int out_size, void* d_ws, size_t ws_size,
                              hipStream_t stream)
{
  const float* loc     = (const float*)d_in[0];
  const float* conf    = (const float*)d_in[1];
  const float* priors  = (const float*)d_in[2];
  const float* tboxes  = (const float*)d_in[3];
  const int*   tlabels = (const int*)d_in[4];
  float* out = (float*)d_out;

  char* ws = (char*)d_ws;
  int*   num_pos = (int*)(ws + 0);        // 64
  float* loss_l  = (float*)(ws + 256);    // 64
  float* ce_pos  = (float*)(ws + 512);    // 64
  float* topk    = (float*)(ws + 768);    // 64
  unsigned long long* bpk = (unsigned long long*)(ws + 1024);  // 64*50*8 = 25600
  float* bto  = (float*)(ws + 26624);
  int*   bti  = (int*)  (ws + 26624 + 4*(size_t)NROWS);
  float* mine = (float*)(ws + 26624 + 8*(size_t)NROWS);

  hipMemsetAsync(ws, 0, 26624, stream);

  dim3 gA((NP + 255)/256, NB);
  k_match<<<gA, 256, 0, stream>>>(priors, tboxes, bto, bti);

  dim3 gA2(NB, NT/TCH, NSEG);
  k_bestprior<<<gA2, 256, 0, stream>>>(priors, tboxes, bpk);

  k_force<<<1, 64, 0, stream>>>(bpk, bto, bti);

  dim3 gC((NP + 255)/256, NB);
  k_ce<<<gC, 256, 0, stream>>>(conf, loc, priors, tboxes, tlabels,
                               bto, bti, mine, ce_pos, loss_l, num_pos);

  k_topk<<<NB, 256, 0, stream>>>(mine, num_pos, topk);

  k_final<<<1, 64, 0, stream>>>(num_pos, loss_l, ce_pos, topk, out);
}

// Round 3
// 781.467 us; speedup vs baseline: 2.8281x; 1.1267x over previous
//
#include <hip/hip_runtime.h>
#include <cstdint>
#include <cstddef>

#define NB 64
#define NP 24564
#define NC 81
#define NROWS (NB*NP)   // 1,572,096
#define NT 50
#define TCH 10          // truths per block in best-prior kernel
#define NSEG 16         // P-segments in best-prior kernel
#define SEGLEN 1536     // 16*1536 = 24576 >= NP

__device__ __forceinline__ unsigned long long umax64(unsigned long long a, unsigned long long b){
  return a > b ? a : b;
}

// ---------------------------------------------------------------------------
// Kernel A: per (b,t) best prior (argmax over P), P split into NSEG segments.
// packed u64 key = (iou_bits<<32) | ~p  -> max = (max iou, then smallest p).
// Wave shuffle reduce -> 4 partials in LDS -> global atomicMax into bpk.
// ---------------------------------------------------------------------------
__global__ __launch_bounds__(256) void k_bestprior(
    const float* __restrict__ priors, const float* __restrict__ tboxes,
    unsigned long long* __restrict__ bpk)
{
  __shared__ float tb[TCH*4];
  __shared__ float ta[TCH];
  __shared__ unsigned long long part[4][TCH];
  const int tid = threadIdx.x;
  const int b  = blockIdx.x;
  const int t0 = blockIdx.y * TCH;
  const int i0 = blockIdx.z * SEGLEN;
  const int iend = min(i0 + SEGLEN, NP);
  if (tid < TCH*4) tb[tid] = tboxes[(b*NT + t0)*4 + tid];
  __syncthreads();
  if (tid < TCH) ta[tid] = (tb[tid*4+2]-tb[tid*4+0]) * (tb[tid*4+3]-tb[tid*4+1]);
  __syncthreads();

  unsigned long long best[TCH];
  #pragma unroll
  for (int j = 0; j < TCH; ++j) best[j] = 0ULL;

  for (int i = i0 + tid; i < iend; i += 256){
    const float4 pr = ((const float4* __restrict__)priors)[i];
    const float px1 = pr.x - 0.5f*pr.z, py1 = pr.y - 0.5f*pr.w;
    const float px2 = pr.x + 0.5f*pr.z, py2 = pr.y + 0.5f*pr.w;
    const float pa  = pr.z * pr.w;
    const unsigned long long low = (unsigned long long)(~(unsigned)i);
    #pragma unroll
    for (int j = 0; j < TCH; ++j){
      float ix = fminf(tb[j*4+2], px2) - fmaxf(tb[j*4+0], px1);
      float iy = fminf(tb[j*4+3], py2) - fmaxf(tb[j*4+1], py1);
      ix = fmaxf(ix, 0.0f); iy = fmaxf(iy, 0.0f);
      const float inter = ix * iy;
      const float iou = inter / (ta[j] + pa - inter);
      const unsigned long long key =
          ((unsigned long long)__float_as_uint(iou) << 32) | low;
      best[j] = umax64(best[j], key);
    }
  }
  // wave-level reduce (64 lanes)
  #pragma unroll
  for (int off = 32; off > 0; off >>= 1){
    #pragma unroll
    for (int j = 0; j < TCH; ++j)
      best[j] = umax64(best[j], __shfl_down(best[j], off));
  }
  const int wv = tid >> 6;
  if ((tid & 63) == 0){
    #pragma unroll
    for (int j = 0; j < TCH; ++j) part[wv][j] = best[j];
  }
  __syncthreads();
  if (tid < TCH){
    const unsigned long long m =
        umax64(umax64(part[0][tid], part[1][tid]),
               umax64(part[2][tid], part[3][tid]));
    atomicMax(&bpk[b*NT + t0 + tid], m);
  }
}

// ---------------------------------------------------------------------------
// Kernel B: fused matching + CE + positive loc loss + counts. One THREAD/row.
//  - recomputes the per-prior best-truth (50 IoUs from LDS)
//  - applies the best-prior override by scanning bpk indices (ascending
//    predicated loop == numpy last-write-wins)
//  - CE row (81 floats, 324 B, 4B-aligned) via enclosing aligned 84-float
//    window (21 float4); boundary elems masked to -inf; gathered logit
//    selected from registers. Block reduce -> 3 atomics per block.
// ---------------------------------------------------------------------------
__global__ __launch_bounds__(256) void k_ce(
    const float* __restrict__ conf, const float* __restrict__ loc,
    const float* __restrict__ priors, const float* __restrict__ tboxes,
    const int* __restrict__ tlabels,
    const unsigned long long* __restrict__ bpk,
    float* __restrict__ mine, float* __restrict__ ce_pos,
    float* __restrict__ loss_l, int* __restrict__ num_pos)
{
  __shared__ float tb[NT*4];
  __shared__ float ta[NT];
  __shared__ int ips[NT];
  __shared__ int tl[NT];
  const int tid = threadIdx.x;
  const int b = blockIdx.y;
  if (tid < NT*4) tb[tid] = tboxes[b*NT*4 + tid];
  else if (tid < NT*4 + NT){
    const int t = tid - NT*4;
    ips[t] = (int)(~(unsigned)(bpk[b*NT + t] & 0xffffffffULL));
  }
  __syncthreads();
  if (tid < NT){
    ta[tid] = (tb[tid*4+2]-tb[tid*4+0]) * (tb[tid*4+3]-tb[tid*4+1]);
    tl[tid] = tlabels[b*NT + tid];
  }
  __syncthreads();

  const int p0 = blockIdx.x*256 + tid;
  const bool active = p0 < NP;
  const int p = active ? p0 : (NP - 1);
  const int r = b*NP + p;
  const size_t e0 = (size_t)r * NC;          // element index of row start
  const size_t a0 = e0 & ~(size_t)3;         // 16B-aligned window start
  const int s = (int)(e0 & 3);               // row offset within window

  // start the streaming loads early
  const float4* __restrict__ c4 = (const float4* __restrict__)conf + (a0 >> 2);
  float4 w[21];
  #pragma unroll
  for (int j = 0; j < 21; ++j) w[j] = c4[j];

  // --- matching: best truth for this prior ---
  const float4 pr = ((const float4* __restrict__)priors)[p];
  const float px1 = pr.x - 0.5f*pr.z, py1 = pr.y - 0.5f*pr.w;
  const float px2 = pr.x + 0.5f*pr.z, py2 = pr.y + 0.5f*pr.w;
  const float pa  = pr.z * pr.w;
  float ov = -1.0f; int ti = 0;
  for (int t = 0; t < NT; ++t){
    float ix = fminf(tb[t*4+2], px2) - fmaxf(tb[t*4+0], px1);
    float iy = fminf(tb[t*4+3], py2) - fmaxf(tb[t*4+1], py1);
    ix = fmaxf(ix, 0.0f); iy = fmaxf(iy, 0.0f);
    const float inter = ix * iy;
    const float iou = inter / (ta[t] + pa - inter);
    if (iou > ov){ ov = iou; ti = t; }        // strict > = first occurrence
  }
  // --- best-prior override (ascending = last-write-wins) ---
  #pragma unroll 10
  for (int t = 0; t < NT; ++t){
    if (ips[t] == p){ ov = 2.0f; ti = t; }
  }
  const int cls = (ov < 0.5f) ? 0 : (tl[ti] + 1);

  // --- softmax CE over the 84-float window ---
  const float NI = -INFINITY;
  // gathered logit from registers BEFORE masking (idx = s+cls is always valid)
  const int idx = s + cls;
  float lg = 0.0f;
  #pragma unroll
  for (int j = 0; j < 21; ++j){
    if ((idx >> 2) == j){
      const float4 t4 = w[j];
      const int q = idx & 3;
      lg = (q == 0) ? t4.x : (q == 1) ? t4.y : (q == 2) ? t4.z : t4.w;
    }
  }
  w[0].x  = (s > 0) ? NI : w[0].x;
  w[0].y  = (s > 1) ? NI : w[0].y;
  w[0].z  = (s > 2) ? NI : w[0].z;
  w[20].y = (s < 1) ? NI : w[20].y;
  w[20].z = (s < 2) ? NI : w[20].z;
  w[20].w = (s < 3) ? NI : w[20].w;

  float m = w[0].w;
  #pragma unroll
  for (int j = 0; j < 21; ++j)
    m = fmaxf(m, fmaxf(fmaxf(w[j].x, w[j].y), fmaxf(w[j].z, w[j].w)));

  float s0 = 0.f, s1 = 0.f, s2 = 0.f, s3 = 0.f;
  #pragma unroll
  for (int j = 0; j < 21; ++j){
    s0 += __expf(w[j].x - m);
    s1 += __expf(w[j].y - m);
    s2 += __expf(w[j].z - m);
    s3 += __expf(w[j].w - m);
  }
  const float ce = m + __logf((s0 + s1) + (s2 + s3)) - lg;

  const bool pos = active && (cls > 0);
  if (active) mine[r] = pos ? 0.0f : ce;

  float cp = pos ? ce : 0.0f;
  float ll = 0.0f;
  int   pc = pos ? 1 : 0;
  if (pos){
    const float tx1 = tb[ti*4+0], ty1 = tb[ti*4+1], tx2 = tb[ti*4+2], ty2 = tb[ti*4+3];
    const float gcx = ((tx1 + tx2)*0.5f - pr.x) / (0.1f*pr.z);
    const float gcy = ((ty1 + ty2)*0.5f - pr.y) / (0.1f*pr.w);
    const float gw  = __logf((tx2 - tx1) / pr.z) * 5.0f;
    const float gh  = __logf((ty2 - ty1) / pr.w) * 5.0f;
    const float4 ld = ((const float4* __restrict__)loc)[r];
    float d, ad;
    d = ld.x - gcx; ad = fabsf(d); ll += (ad < 1.0f) ? 0.5f*d*d : ad - 0.5f;
    d = ld.y - gcy; ad = fabsf(d); ll += (ad < 1.0f) ? 0.5f*d*d : ad - 0.5f;
    d = ld.z - gw;  ad = fabsf(d); ll += (ad < 1.0f) ? 0.5f*d*d : ad - 0.5f;
    d = ld.w - gh;  ad = fabsf(d); ll += (ad < 1.0f) ? 0.5f*d*d : ad - 0.5f;
  }

  // wave -> block reduction, 3 atomics per block total
  #pragma unroll
  for (int off = 32; off > 0; off >>= 1){
    cp += __shfl_down(cp, off);
    ll += __shfl_down(ll, off);
    pc += __shfl_down(pc, off);
  }
  __shared__ float rcp[4], rll[4];
  __shared__ int rpc[4];
  const int wv = tid >> 6;
  if ((tid & 63) == 0){ rcp[wv] = cp; rll[wv] = ll; rpc[wv] = pc; }
  __syncthreads();
  if (tid == 0){
    atomicAdd(&ce_pos[b], (rcp[0]+rcp[1])+(rcp[2]+rcp[3]));
    atomicAdd(&loss_l[b], (rll[0]+rll[1])+(rll[2]+rll[3]));
    atomicAdd(&num_pos[b], (rpc[0]+rpc[1])+(rpc[2]+rpc[3]));
  }
}

// ---------------------------------------------------------------------------
// Kernel D: exact top-k sum per image via 4-pass radix select on float bits.
// 1024 threads; NP = 6141 float4 exactly; single-wave suffix scan (3 syncs
// per pass instead of 16).
// ---------------------------------------------------------------------------
__global__ __launch_bounds__(1024) void k_topk(
    const float* __restrict__ mine, const int* __restrict__ num_pos,
    float* __restrict__ topk)
{
  const int b = blockIdx.x;
  const int tid = threadIdx.x;
  const float4* __restrict__ d4 =
      (const float4* __restrict__)(mine + (size_t)b * NP);   // 6141 float4
  const int k = min(3 * num_pos[b], NP - 1);

  __shared__ unsigned hist[256];
  __shared__ unsigned s_prefix;
  __shared__ int s_rem;
  __shared__ float wsum[16];

  if (k <= 0){
    if (tid == 0) topk[b] = 0.0f;
    return;
  }
  if (tid == 0){ s_prefix = 0u; s_rem = k; }

  for (int pass = 0; pass < 4; ++pass){
    const int shift = 24 - pass*8;
    if (tid < 256) hist[tid] = 0u;
    __syncthreads();                          // (A) hist zeroed, sel stable
    const unsigned pref = s_prefix;
    const int rem = s_rem;
    for (int i = tid; i < 6141; i += 1024){
      const float4 v = d4[i];
      unsigned u;
      u = __float_as_uint(v.x);
      if (pass == 0 || (u >> (shift+8)) == pref) atomicAdd(&hist[(u>>shift)&255u], 1u);
      u = __float_as_uint(v.y);
      if (pass == 0 || (u >> (shift+8)) == pref) atomicAdd(&hist[(u>>shift)&255u], 1u);
      u = __float_as_uint(v.z);
      if (pass == 0 || (u >> (shift+8)) == pref) atomicAdd(&hist[(u>>shift)&255u], 1u);
      u = __float_as_uint(v.w);
      if (pass == 0 || (u >> (shift+8)) == pref) atomicAdd(&hist[(u>>shift)&255u], 1u);
    }
    __syncthreads();                          // (B) hist complete
    if (tid < 64){
      const unsigned h0 = hist[4*tid], h1 = hist[4*tid+1];
      const unsigned h2 = hist[4*tid+2], h3 = hist[4*tid+3];
      const unsigned pl = h0 + h1 + h2 + h3;
      unsigned S = pl;                        // inclusive suffix over lanes
      #pragma unroll
      for (int off = 1; off < 64; off <<= 1){
        const unsigned v = __shfl_down(S, off);
        if (tid + off < 64) S += v;
      }
      const unsigned Sn = S - pl;             // suffix starting at bin 4*tid+4
      const unsigned t3 = h3 + Sn;
      const unsigned t2 = h2 + t3;
      const unsigned t1 = h1 + t2;
      const unsigned t0 = h0 + t1;
      if ((int)t0 >= rem && (int)t1 < rem){ s_prefix = (pref<<8) | (4u*tid+0u); s_rem = rem - (int)t1; }
      if ((int)t1 >= rem && (int)t2 < rem){ s_prefix = (pref<<8) | (4u*tid+1u); s_rem = rem - (int)t2; }
      if ((int)t2 >= rem && (int)t3 < rem){ s_prefix = (pref<<8) | (4u*tid+2u); s_rem = rem - (int)t3; }
      if ((int)t3 >= rem && (int)Sn < rem){ s_prefix = (pref<<8) | (4u*tid+3u); s_rem = rem - (int)Sn; }
    }
    __syncthreads();                          // (C) selection visible
  }

  const unsigned kb = s_prefix;
  const int rem = s_rem;
  const float kv = __uint_as_float(kb);
  float acc = 0.0f;
  for (int i = tid; i < 6141; i += 1024){
    const float4 v = d4[i];
    if (__float_as_uint(v.x) > kb) acc += v.x;
    if (__float_as_uint(v.y) > kb) acc += v.y;
    if (__float_as_uint(v.z) > kb) acc += v.z;
    if (__float_as_uint(v.w) > kb) acc += v.w;
  }
  #pragma unroll
  for (int off = 32; off > 0; off >>= 1) acc += __shfl_down(acc, off);
  if ((tid & 63) == 0) wsum[tid >> 6] = acc;
  __syncthreads();
  if (tid == 0){
    float s = 0.0f;
    #pragma unroll
    for (int j = 0; j < 16; ++j) s += wsum[j];
    topk[b] = s + (float)rem * kv;
  }
}

// ---------------------------------------------------------------------------
// Kernel E: final combine
// ---------------------------------------------------------------------------
__global__ void k_final(const int* __restrict__ num_pos,
                        const float* __restrict__ loss_l,
                        const float* __restrict__ ce_pos,
                        const float* __restrict__ topk,
                        float* __restrict__ out)
{
  const int tid = threadIdx.x;
  int   np = num_pos[tid];
  float ll = loss_l[tid];
  float cp = ce_pos[tid];
  float tk = topk[tid];
  #pragma unroll
  for (int off = 32; off > 0; off >>= 1){
    np += __shfl_down(np, off);
    ll += __shfl_down(ll, off);
    cp += __shfl_down(cp, off);
    tk += __shfl_down(tk, off);
  }
  if (tid == 0){
    const float n = (float)max(np, 1);
    out[0] = ll / n;
    out[1] = (cp + tk) / n;
  }
}

// ---------------------------------------------------------------------------
extern "C" void kernel_launch(void* const* d_in, const int* in_sizes, int n_in,
                              void* d_out, int out_size, void* d_ws, size_t ws_size,
                              hipStream_t stream)
{
  const float* loc     = (const float*)d_in[0];
  const float* conf    = (const float*)d_in[1];
  const float* priors  = (const float*)d_in[2];
  const float* tboxes  = (const float*)d_in[3];
  const int*   tlabels = (const int*)d_in[4];
  float* out = (float*)d_out;

  char* ws = (char*)d_ws;
  int*   num_pos = (int*)(ws + 0);        // 64
  float* loss_l  = (float*)(ws + 256);    // 64
  float* ce_pos  = (float*)(ws + 512);    // 64
  float* topk    = (float*)(ws + 768);    // 64
  unsigned long long* bpk = (unsigned long long*)(ws + 1024);  // 64*50*8
  float* mine = (float*)(ws + 26624);     // NROWS floats, 16B aligned

  hipMemsetAsync(ws, 0, 26624, stream);

  dim3 gA(NB, NT/TCH, NSEG);
  k_bestprior<<<gA, 256, 0, stream>>>(priors, tboxes, bpk);

  dim3 gC((NP + 255)/256, NB);
  k_ce<<<gC, 256, 0, stream>>>(conf, loc, priors, tboxes, tlabels,
                               bpk, mine, ce_pos, loss_l, num_pos);

  k_topk<<<NB, 1024, 0, stream>>>(mine, num_pos, topk);

  k_final<<<1, 64, 0, stream>>>(num_pos, loss_l, ce_pos, topk, out);
}